// Round 13
// baseline (48.169 us; speedup 1.0000x reference)
//
#include <hip/hip_runtime.h>
#include <math.h>

#define NB 1024
#define NC 64
#define NH 64
#define ND 256
#define NHID 256

typedef float f4 __attribute__((ext_vector_type(4)));

// ws layout (floats): [0..255] = v_h, [256] = mask mode (int),
// [1024 .. 1024+64*256)      = P1 partials (needs ws >=    69,632 B)
// [32768 .. 32768+1024*256)  = uv[b][d]    (needs ws >= 1,179,648 B)
#define WS_PART_OFF 1024
#define WS_UV_OFF   32768

// mask storage modes: 0 = int32, 1 = byte (bool), 2 = float32
__device__ __forceinline__ bool read_mask(const void* m, int idx, int mode) {
  if (mode == 2) return ((const float*)m)[idx] != 0.0f;
  if (mode == 1) return ((const unsigned char*)m)[idx] != 0;
  return ((const int*)m)[idx] != 0;
}

__device__ __forceinline__ void detect_mode(const unsigned int* mask_cand,
                                            const unsigned int* mask_hist,
                                            int* dst) {
  int sawf = 0; unsigned int big = 0;
  for (int i = 0; i < 32; ++i) {
    unsigned int a = mask_hist[i], b = mask_cand[i];
    if (a == 0x3f800000u || b == 0x3f800000u) sawf = 1;
    if ((a > 1u && a != 0x3f800000u) || (b > 1u && b != 0x3f800000u)) big = 1;
  }
  *dst = sawf ? 2 : (big ? 1 : 0);
}

__device__ __forceinline__ float dot4(f4 a, f4 b) {
  return fmaf(a.x, b.x, fmaf(a.y, b.y, fmaf(a.z, b.z, a.w * b.w)));
}

#define BFLY(p) { p += __shfl_xor(p, 32); p += __shfl_xor(p, 16); p += __shfl_xor(p, 8); \
                  p += __shfl_xor(p, 4);  p += __shfl_xor(p, 2);  p += __shfl_xor(p, 1); }

// ---- P1: 64 blocks x 256 threads: partial v_h over 4 j-rows each ----
__global__ __launch_bounds__(256) void precompute_p1(
    const float* __restrict__ W1, const float* __restrict__ W2,
    float* __restrict__ ws)
{
  const int g = blockIdx.x;
  const int d = threadIdx.x;
  float acc = 0.f;
  #pragma unroll
  for (int jj = 0; jj < 4; ++jj) {
    int j = g * 4 + jj;
    acc = fmaf(W1[(size_t)j * (2 * ND) + ND + d], W2[j], acc);
  }
  ws[WS_PART_OFF + g * ND + d] = acc;
}

// ---- P2: 1 block x 256 threads: reduce partials, detect mask mode ----
__global__ __launch_bounds__(256) void precompute_p2(
    const unsigned int* __restrict__ mask_cand,
    const unsigned int* __restrict__ mask_hist,
    float* __restrict__ ws)
{
  const int d = threadIdx.x;
  float acc = 0.f;
  #pragma unroll 8
  for (int g = 0; g < 64; ++g) acc += ws[WS_PART_OFF + g * ND + d];
  ws[d] = acc;
  if (d == 0) detect_mode(mask_cand, mask_hist, (int*)ws + ND);
}

// ---- fallback single-block precompute (small ws) ----
__global__ __launch_bounds__(1024) void precompute_fallback(
    const float* __restrict__ W1, const float* __restrict__ W2,
    const unsigned int* __restrict__ mask_cand,
    const unsigned int* __restrict__ mask_hist,
    float* __restrict__ ws)
{
  __shared__ float w2_lds[NHID];
  __shared__ float partial[4][ND];
  int t = threadIdx.x;
  if (t < NHID) w2_lds[t] = W2[t];
  __syncthreads();
  int d = t & (ND - 1);
  int g = t >> 8;
  float acc = 0.f;
  #pragma unroll 8
  for (int j = g * 64; j < g * 64 + 64; ++j)
    acc = fmaf(W1[(size_t)j * (2 * ND) + ND + d], w2_lds[j], acc);
  partial[g][d] = acc;
  __syncthreads();
  if (t < ND)
    ws[t] = partial[0][t] + partial[1][t] + partial[2][t] + partial[3][t];
  if (t == 0) detect_mode(mask_cand, mask_hist, (int*)ws + ND);
}

// Load 8 consecutive rows (h0..h0+7) as f4 per lane: 8 x 1 KB contiguous.
#define LOADB(R0,R1,R2,R3,R4,R5,R6,R7, H0)                                     \
  R0 = hp4[((H0) + 0) * 64 + lane]; R1 = hp4[((H0) + 1) * 64 + lane];          \
  R2 = hp4[((H0) + 2) * 64 + lane]; R3 = hp4[((H0) + 3) * 64 + lane];          \
  R4 = hp4[((H0) + 4) * 64 + lane]; R5 = hp4[((H0) + 5) * 64 + lane];          \
  R6 = hp4[((H0) + 6) * 64 + lane]; R7 = hp4[((H0) + 7) * 64 + lane];

// Online-softmax batch update over 8 rows (flash style; lanes redundantly
// carry scalar state m,s; acc is this lane's 4 output columns).
#define PROCB(R0,R1,R2,R3,R4,R5,R6,R7, H0)                                     \
  {                                                                            \
    float p0 = dot4(R0, vhq), p1 = dot4(R1, vhq), p2 = dot4(R2, vhq),          \
          p3 = dot4(R3, vhq), p4 = dot4(R4, vhq), p5 = dot4(R5, vhq),          \
          p6 = dot4(R6, vhq), p7 = dot4(R7, vhq);                              \
    BFLY(p0) BFLY(p1) BFLY(p2) BFLY(p3) BFLY(p4) BFLY(p5) BFLY(p6) BFLY(p7)    \
    p0 = ((mh >> ((H0) + 0)) & 1) ? p0 : -3.0e38f;                             \
    p1 = ((mh >> ((H0) + 1)) & 1) ? p1 : -3.0e38f;                             \
    p2 = ((mh >> ((H0) + 2)) & 1) ? p2 : -3.0e38f;                             \
    p3 = ((mh >> ((H0) + 3)) & 1) ? p3 : -3.0e38f;                             \
    p4 = ((mh >> ((H0) + 4)) & 1) ? p4 : -3.0e38f;                             \
    p5 = ((mh >> ((H0) + 5)) & 1) ? p5 : -3.0e38f;                             \
    p6 = ((mh >> ((H0) + 6)) & 1) ? p6 : -3.0e38f;                             \
    p7 = ((mh >> ((H0) + 7)) & 1) ? p7 : -3.0e38f;                             \
    float pm = fmaxf(fmaxf(fmaxf(p0, p1), fmaxf(p2, p3)),                      \
                     fmaxf(fmaxf(p4, p5), fmaxf(p6, p7)));                     \
    float mn = fmaxf(mrun, pm);                                                \
    float sc = expf(mrun - mn);                                                \
    float e0 = expf(p0 - mn), e1 = expf(p1 - mn), e2 = expf(p2 - mn),          \
          e3 = expf(p3 - mn), e4 = expf(p4 - mn), e5 = expf(p5 - mn),          \
          e6 = expf(p6 - mn), e7 = expf(p7 - mn);                              \
    srun = srun * sc + ((e0 + e1) + (e2 + e3)) + ((e4 + e5) + (e6 + e7));      \
    acc = acc * sc;                                                            \
    acc += e0 * R0; acc += e1 * R1; acc += e2 * R2; acc += e3 * R3;            \
    acc += e4 * R4; acc += e5 * R5; acc += e6 * R6; acc += e7 * R7;            \
    mrun = mn;                                                                 \
  }

// ---- A: read-only flash. One wave per b; 4 register sets = 24 loads in
// flight (launch_bounds(256,1) gives the allocator headroom so it does NOT
// sink the prefetch to save VGPRs — R12's defeat, VGPR=52). Output: uv[b]
// (1 KB). No barriers, no LDS, no store burst. ----
__global__ __launch_bounds__(256, 1) void score_uv_flash(
    const float* __restrict__ hist,
    const void* __restrict__ mask_hist_v,
    const float* __restrict__ ws,
    float* __restrict__ uv_out)
{
  const int tid = threadIdx.x, lane = tid & 63, w = tid >> 6;
  const int b = blockIdx.x * 4 + w;

  const int mode = ((const int*)ws)[ND];
  const f4* hp4 = reinterpret_cast<const f4*>(hist) + (size_t)b * 4096;
  const f4 vhq = reinterpret_cast<const f4*>(ws)[lane];   // 1 KB, L1-hot

  const unsigned long long mh =
      __ballot(read_mask(mask_hist_v, b * NH + lane, mode));

  float mrun = -3.0e38f, srun = 0.f;
  f4 acc = {0.f, 0.f, 0.f, 0.f};
  f4 x0, x1, x2, x3, x4, x5, x6, x7;
  f4 y0, y1, y2, y3, y4, y5, y6, y7;
  f4 z0, z1, z2, z3, z4, z5, z6, z7;
  f4 u0, u1, u2, u3, u4, u5, u6, u7;

  // 4-deep pipeline: 24-32 loads in flight ahead of each consume
  LOADB(x0,x1,x2,x3,x4,x5,x6,x7, 0)
  LOADB(y0,y1,y2,y3,y4,y5,y6,y7, 8)
  LOADB(z0,z1,z2,z3,z4,z5,z6,z7, 16)
  LOADB(u0,u1,u2,u3,u4,u5,u6,u7, 24)
  PROCB(x0,x1,x2,x3,x4,x5,x6,x7, 0)
  LOADB(x0,x1,x2,x3,x4,x5,x6,x7, 32)
  PROCB(y0,y1,y2,y3,y4,y5,y6,y7, 8)
  LOADB(y0,y1,y2,y3,y4,y5,y6,y7, 40)
  PROCB(z0,z1,z2,z3,z4,z5,z6,z7, 16)
  LOADB(z0,z1,z2,z3,z4,z5,z6,z7, 48)
  PROCB(u0,u1,u2,u3,u4,u5,u6,u7, 24)
  LOADB(u0,u1,u2,u3,u4,u5,u6,u7, 56)
  PROCB(x0,x1,x2,x3,x4,x5,x6,x7, 32)
  PROCB(y0,y1,y2,y3,y4,y5,y6,y7, 40)
  PROCB(z0,z1,z2,z3,z4,z5,z6,z7, 48)
  PROCB(u0,u1,u2,u3,u4,u5,u6,u7, 56)

  const f4 uv = acc * (1.0f / srun);
  reinterpret_cast<f4*>(uv_out)[b * 64 + lane] = uv;   // 1 KB contiguous
}

// ---- B: pure-write broadcast (fill regime). 4096 blocks; block (b,q)
// NT-stores rows q*16..q*16+15 (16 KB) after reading 1 KB uv + 16 masks. ----
__global__ __launch_bounds__(256) void broadcast_kernel(
    const float* __restrict__ uv_src,
    const void* __restrict__ mask_cand_v,
    const float* __restrict__ ws,
    float* __restrict__ out)
{
  const int bid = blockIdx.x;
  const int b = bid >> 2, q = bid & 3;
  const int t = threadIdx.x, lane = t & 63, g = t >> 6;
  const int mode = ((const int*)ws)[ND];
  const f4 uv = reinterpret_cast<const f4*>(uv_src)[b * 64 + lane];
  f4* ob4 = reinterpret_cast<f4*>(out) + (size_t)b * 4096;
  const f4 zero = {0.f, 0.f, 0.f, 0.f};
  #pragma unroll
  for (int j = 0; j < 4; ++j) {
    int c = q * 16 + g * 4 + j;        // uniform per wave -> 1 KB contiguous
    bool mc = read_mask(mask_cand_v, b * NC + c, mode);
    f4 val = mc ? uv : zero;
    __builtin_nontemporal_store(val, &ob4[c * 64 + lane]);
  }
}

// ---- fallback (small ws): R12 flash with inline store sweep, known-good ----
__global__ __launch_bounds__(256) void flash_fallback_kernel(
    const float* __restrict__ hist,
    const void* __restrict__ mask_cand_v,
    const void* __restrict__ mask_hist_v,
    const float* __restrict__ ws,
    float* __restrict__ out)
{
  const int tid = threadIdx.x, lane = tid & 63, w = tid >> 6;
  const int b = blockIdx.x * 4 + w;

  const int mode = ((const int*)ws)[ND];
  const f4* hp4 = reinterpret_cast<const f4*>(hist) + (size_t)b * 4096;
  const f4 vhq = reinterpret_cast<const f4*>(ws)[lane];

  const unsigned long long mh =
      __ballot(read_mask(mask_hist_v, b * NH + lane, mode));
  const unsigned long long mc =
      __ballot(read_mask(mask_cand_v, b * NC + lane, mode));

  float mrun = -3.0e38f, srun = 0.f;
  f4 acc = {0.f, 0.f, 0.f, 0.f};
  f4 x0, x1, x2, x3, x4, x5, x6, x7;
  f4 y0, y1, y2, y3, y4, y5, y6, y7;

  LOADB(x0,x1,x2,x3,x4,x5,x6,x7, 0)
  LOADB(y0,y1,y2,y3,y4,y5,y6,y7, 8)
  PROCB(x0,x1,x2,x3,x4,x5,x6,x7, 0)
  LOADB(x0,x1,x2,x3,x4,x5,x6,x7, 16)
  PROCB(y0,y1,y2,y3,y4,y5,y6,y7, 8)
  LOADB(y0,y1,y2,y3,y4,y5,y6,y7, 24)
  PROCB(x0,x1,x2,x3,x4,x5,x6,x7, 16)
  LOADB(x0,x1,x2,x3,x4,x5,x6,x7, 32)
  PROCB(y0,y1,y2,y3,y4,y5,y6,y7, 24)
  LOADB(y0,y1,y2,y3,y4,y5,y6,y7, 40)
  PROCB(x0,x1,x2,x3,x4,x5,x6,x7, 32)
  LOADB(x0,x1,x2,x3,x4,x5,x6,x7, 48)
  PROCB(y0,y1,y2,y3,y4,y5,y6,y7, 40)
  LOADB(y0,y1,y2,y3,y4,y5,y6,y7, 56)
  PROCB(x0,x1,x2,x3,x4,x5,x6,x7, 48)
  PROCB(y0,y1,y2,y3,y4,y5,y6,y7, 56)

  const f4 uv = acc * (1.0f / srun);
  const f4 zero = {0.f, 0.f, 0.f, 0.f};
  f4* ob4 = reinterpret_cast<f4*>(out) + (size_t)b * 4096;
  #pragma unroll
  for (int c = 0; c < 64; ++c)
    ob4[c * 64 + lane] = ((mc >> c) & 1ull) ? uv : zero;
}

extern "C" void kernel_launch(void* const* d_in, const int* in_sizes, int n_in,
                              void* d_out, int out_size, void* d_ws, size_t ws_size,
                              hipStream_t stream) {
  (void)in_sizes; (void)n_in; (void)out_size;
  // inputs: 0 cand [B,C,D] (UNUSED — softmax shift-invariance kills the
  // candidate term), 1 hist [B,H,D], 2 mask_cand, 3 mask_hist,
  // 4 W1 [HID,2D], 5 b1 (unused), 6 W2 [1,HID], 7 b2 (unused)
  const float* hist = (const float*)d_in[1];
  const void*  mask_cand = d_in[2];
  const void*  mask_hist = d_in[3];
  const float* W1 = (const float*)d_in[4];
  const float* W2 = (const float*)d_in[6];
  float* ws = (float*)d_ws;
  float* out = (float*)d_out;

  const bool mid = ws_size >= (size_t)(WS_PART_OFF + 64 * ND) * sizeof(float);
  const bool big = ws_size >= (size_t)(WS_UV_OFF + NB * ND) * sizeof(float);

  if (mid) {
    precompute_p1<<<64, 256, 0, stream>>>(W1, W2, ws);
    precompute_p2<<<1, 256, 0, stream>>>(
        (const unsigned int*)mask_cand, (const unsigned int*)mask_hist, ws);
  } else {
    precompute_fallback<<<1, 1024, 0, stream>>>(
        W1, W2, (const unsigned int*)mask_cand, (const unsigned int*)mask_hist, ws);
  }

  if (big) {
    score_uv_flash<<<NB / 4, 256, 0, stream>>>(hist, mask_hist, ws, ws + WS_UV_OFF);
    broadcast_kernel<<<NB * 4, 256, 0, stream>>>(ws + WS_UV_OFF, mask_cand, ws, out);
  } else {
    flash_fallback_kernel<<<NB / 4, 256, 0, stream>>>(hist, mask_cand, mask_hist, ws, out);
  }
}

// Round 14
// 45.901 us; speedup vs baseline: 1.0494x; 1.0494x over previous
//
#include <hip/hip_runtime.h>
#include <math.h>

#define NB 1024
#define NC 64
#define NH 64
#define ND 256
#define NHID 256

typedef float f4 __attribute__((ext_vector_type(4)));

// ws float offsets:
// [0..255] v_h, [256] mask mode, [1024..17408) P1 partials,
// [20480..24576) m/s per (b,half) (4 floats per b),
// [32768..294912) half-0 weighted partials (1024*256),
// [294912..557056) half-1 weighted partials.
#define WS_PART_OFF 1024
#define WS_MS_OFF   20480
#define WS_P0_OFF   32768
#define WS_P1_OFF   (32768 + NB * ND)
#define WS_NEED_F   (WS_P1_OFF + NB * ND)

// mask storage modes: 0 = int32, 1 = byte (bool), 2 = float32
__device__ __forceinline__ bool read_mask(const void* m, int idx, int mode) {
  if (mode == 2) return ((const float*)m)[idx] != 0.0f;
  if (mode == 1) return ((const unsigned char*)m)[idx] != 0;
  return ((const int*)m)[idx] != 0;
}

__device__ __forceinline__ void detect_mode(const unsigned int* mask_cand,
                                            const unsigned int* mask_hist,
                                            int* dst) {
  int sawf = 0; unsigned int big = 0;
  for (int i = 0; i < 32; ++i) {
    unsigned int a = mask_hist[i], b = mask_cand[i];
    if (a == 0x3f800000u || b == 0x3f800000u) sawf = 1;
    if ((a > 1u && a != 0x3f800000u) || (b > 1u && b != 0x3f800000u)) big = 1;
  }
  *dst = sawf ? 2 : (big ? 1 : 0);
}

__device__ __forceinline__ float dot4(f4 a, f4 b) {
  return fmaf(a.x, b.x, fmaf(a.y, b.y, fmaf(a.z, b.z, a.w * b.w)));
}

#define BFLY(p) { p += __shfl_xor(p, 32); p += __shfl_xor(p, 16); p += __shfl_xor(p, 8); \
                  p += __shfl_xor(p, 4);  p += __shfl_xor(p, 2);  p += __shfl_xor(p, 1); }

// ---- P1/P2 precompute of v_h (unchanged, proven) ----
__global__ __launch_bounds__(256) void precompute_p1(
    const float* __restrict__ W1, const float* __restrict__ W2,
    float* __restrict__ ws)
{
  const int g = blockIdx.x;
  const int d = threadIdx.x;
  float acc = 0.f;
  #pragma unroll
  for (int jj = 0; jj < 4; ++jj) {
    int j = g * 4 + jj;
    acc = fmaf(W1[(size_t)j * (2 * ND) + ND + d], W2[j], acc);
  }
  ws[WS_PART_OFF + g * ND + d] = acc;
}

__global__ __launch_bounds__(256) void precompute_p2(
    const unsigned int* __restrict__ mask_cand,
    const unsigned int* __restrict__ mask_hist,
    float* __restrict__ ws)
{
  const int d = threadIdx.x;
  float acc = 0.f;
  #pragma unroll 8
  for (int g = 0; g < 64; ++g) acc += ws[WS_PART_OFF + g * ND + d];
  ws[d] = acc;
  if (d == 0) detect_mode(mask_cand, mask_hist, (int*)ws + ND);
}

__global__ __launch_bounds__(1024) void precompute_fallback(
    const float* __restrict__ W1, const float* __restrict__ W2,
    const unsigned int* __restrict__ mask_cand,
    const unsigned int* __restrict__ mask_hist,
    float* __restrict__ ws)
{
  __shared__ float w2_lds[NHID];
  __shared__ float partial[4][ND];
  int t = threadIdx.x;
  if (t < NHID) w2_lds[t] = W2[t];
  __syncthreads();
  int d = t & (ND - 1);
  int g = t >> 8;
  float acc = 0.f;
  #pragma unroll 8
  for (int j = g * 64; j < g * 64 + 64; ++j)
    acc = fmaf(W1[(size_t)j * (2 * ND) + ND + d], w2_lds[j], acc);
  partial[g][d] = acc;
  __syncthreads();
  if (t < ND)
    ws[t] = partial[0][t] + partial[1][t] + partial[2][t] + partial[3][t];
  if (t == 0) detect_mode(mask_cand, mask_hist, (int*)ws + ND);
}

// Load batch k (8 rows) of this wave's half: lane (g=lane>>3, sub=lane&7)
// reads 8 f4 of row k*8+g at f4-cols sub+8i. Each instr = 8 x 128B lines.
#define GLOAD(R0,R1,R2,R3,R4,R5,R6,R7, K)                                      \
  {                                                                            \
    const f4* rp_ = hb4 + ((K) * 8 + g) * 64 + sub;                            \
    R0 = rp_[0];  R1 = rp_[8];  R2 = rp_[16]; R3 = rp_[24];                    \
    R4 = rp_[32]; R5 = rp_[40]; R6 = rp_[48]; R7 = rp_[56];                    \
  }

// Grouped flash batch update: 9 shfl + 1-2 exp per lane per 8 rows.
#define GPROC(R0,R1,R2,R3,R4,R5,R6,R7, K)                                      \
  {                                                                            \
    float p = dot4(R0, vh0) + dot4(R1, vh1) + dot4(R2, vh2) + dot4(R3, vh3)    \
            + dot4(R4, vh4) + dot4(R5, vh5) + dot4(R6, vh6) + dot4(R7, vh7);   \
    p += __shfl_xor(p, 1); p += __shfl_xor(p, 2); p += __shfl_xor(p, 4);       \
    const int hrow_ = half * 32 + (K) * 8 + g;                                 \
    const bool mb_ = (mh >> hrow_) & 1ull;                                     \
    p = mb_ ? p : -3.0e38f;                                                    \
    float pm_ = p;                                                             \
    pm_ = fmaxf(pm_, __shfl_xor(pm_, 8));                                      \
    pm_ = fmaxf(pm_, __shfl_xor(pm_, 16));                                     \
    pm_ = fmaxf(pm_, __shfl_xor(pm_, 32));                                     \
    float mn_ = fmaxf(mrun, pm_);                                              \
    float sc_ = expf(mrun - mn_);                                              \
    float e_ = mb_ ? expf(p - mn_) : 0.f;                                      \
    float ts_ = e_;                                                            \
    ts_ += __shfl_xor(ts_, 8); ts_ += __shfl_xor(ts_, 16);                     \
    ts_ += __shfl_xor(ts_, 32);                                                \
    srun = srun * sc_ + ts_;                                                   \
    a0 = a0 * sc_ + e_ * R0; a1 = a1 * sc_ + e_ * R1;                          \
    a2 = a2 * sc_ + e_ * R2; a3 = a3 * sc_ + e_ * R3;                          \
    a4 = a4 * sc_ + e_ * R4; a5 = a5 * sc_ + e_ * R5;                          \
    a6 = a6 * sc_ + e_ * R6; a7 = a7 * sc_ + e_ * R7;                          \
    mrun = mn_;                                                                \
  }

// ---- A: grouped flash scores. One wave per (b, half): 2048 waves, 8/CU.
// 32 rows per wave in 4 batches, 2-deep load pipeline. Output: flash state
// (m,s) + weighted partial (1 KB) per (b,half). No block barriers. ----
__global__ __launch_bounds__(512, 2) void score2_kernel(
    const float* __restrict__ hist,
    const void* __restrict__ mask_hist_v,
    float* __restrict__ ws)
{
  const int t = threadIdx.x, lane = t & 63, w = t >> 6;
  const int W = blockIdx.x * 8 + w;          // 0..2047
  const int b = W >> 1, half = W & 1;
  const int sub = lane & 7, g = lane >> 3;

  __shared__ f4 lds[8][64][8];               // 8 KB per wave, 64 KB per block

  const int mode = ((const int*)ws)[ND];
  const f4* hb4 = reinterpret_cast<const f4*>(hist)
                + (size_t)b * 4096 + half * 32 * 64;
  const f4* ws4 = reinterpret_cast<const f4*>(ws);
  const f4 vh0 = ws4[sub +  0], vh1 = ws4[sub +  8];
  const f4 vh2 = ws4[sub + 16], vh3 = ws4[sub + 24];
  const f4 vh4 = ws4[sub + 32], vh5 = ws4[sub + 40];
  const f4 vh6 = ws4[sub + 48], vh7 = ws4[sub + 56];

  const unsigned long long mh =
      __ballot(read_mask(mask_hist_v, b * NH + lane, mode));

  float mrun = -3.0e38f, srun = 0.f;
  f4 a0 = {0,0,0,0}, a1 = a0, a2 = a0, a3 = a0,
     a4 = a0, a5 = a0, a6 = a0, a7 = a0;
  f4 x0, x1, x2, x3, x4, x5, x6, x7;
  f4 y0, y1, y2, y3, y4, y5, y6, y7;

  GLOAD(x0,x1,x2,x3,x4,x5,x6,x7, 0)
  GLOAD(y0,y1,y2,y3,y4,y5,y6,y7, 1)
  GPROC(x0,x1,x2,x3,x4,x5,x6,x7, 0)
  GLOAD(x0,x1,x2,x3,x4,x5,x6,x7, 2)
  GPROC(y0,y1,y2,y3,y4,y5,y6,y7, 1)
  GLOAD(y0,y1,y2,y3,y4,y5,y6,y7, 3)
  GPROC(x0,x1,x2,x3,x4,x5,x6,x7, 2)
  GPROC(y0,y1,y2,y3,y4,y5,y6,y7, 3)

  // fold the 8 lane-groups' partials via per-wave LDS transpose (single-wave
  // coherence: lgkmcnt fence, no block barrier needed)
  lds[w][lane][0] = a0; lds[w][lane][1] = a1;
  lds[w][lane][2] = a2; lds[w][lane][3] = a3;
  lds[w][lane][4] = a4; lds[w][lane][5] = a5;
  lds[w][lane][6] = a6; lds[w][lane][7] = a7;
  asm volatile("s_waitcnt lgkmcnt(0)" ::: "memory");
  f4 mg = {0,0,0,0};
  #pragma unroll
  for (int g2 = 0; g2 < 8; ++g2)
    mg += lds[w][(lane & 7) + 8 * g2][lane >> 3];

  reinterpret_cast<f4*>(ws + (half ? WS_P1_OFF : WS_P0_OFF) + b * ND)[lane] = mg;
  if (lane == 0) {
    ws[WS_MS_OFF + b * 4 + half * 2 + 0] = mrun;
    ws[WS_MS_OFF + b * 4 + half * 2 + 1] = srun;
  }
}

// ---- B: merge halves + pure-write broadcast (proven ~10-12 us shape).
// Block (b,q) NT-stores rows q*16..q*16+15. ----
__global__ __launch_bounds__(256) void bcast2_kernel(
    const void* __restrict__ mask_cand_v,
    const float* __restrict__ ws,
    float* __restrict__ out)
{
  const int bid = blockIdx.x;
  const int b = bid >> 2, q = bid & 3;
  const int t = threadIdx.x, lane = t & 63, g = t >> 6;
  const int mode = ((const int*)ws)[ND];

  const float m0 = ws[WS_MS_OFF + b * 4 + 0], s0 = ws[WS_MS_OFF + b * 4 + 1];
  const float m1 = ws[WS_MS_OFF + b * 4 + 2], s1 = ws[WS_MS_OFF + b * 4 + 3];
  const float mm = fmaxf(m0, m1);
  const float w0 = expf(m0 - mm), w1 = expf(m1 - mm);
  const float inv = 1.0f / (s0 * w0 + s1 * w1);

  const f4 p0 = reinterpret_cast<const f4*>(ws + WS_P0_OFF + b * ND)[lane];
  const f4 p1 = reinterpret_cast<const f4*>(ws + WS_P1_OFF + b * ND)[lane];
  const f4 uv = (p0 * w0 + p1 * w1) * inv;

  f4* ob4 = reinterpret_cast<f4*>(out) + (size_t)b * 4096;
  const f4 zero = {0.f, 0.f, 0.f, 0.f};
  #pragma unroll
  for (int j = 0; j < 4; ++j) {
    int c = q * 16 + g * 4 + j;        // uniform per wave -> 1 KB contiguous
    bool mc = read_mask(mask_cand_v, b * NC + c, mode);
    f4 val = mc ? uv : zero;
    __builtin_nontemporal_store(val, &ob4[c * 64 + lane]);
  }
}

// ---- fallback (small ws): R12 flash fused, known-good ~40 us ----
#define LOADB(R0,R1,R2,R3,R4,R5,R6,R7, H0)                                     \
  R0 = hp4[((H0) + 0) * 64 + lane]; R1 = hp4[((H0) + 1) * 64 + lane];          \
  R2 = hp4[((H0) + 2) * 64 + lane]; R3 = hp4[((H0) + 3) * 64 + lane];          \
  R4 = hp4[((H0) + 4) * 64 + lane]; R5 = hp4[((H0) + 5) * 64 + lane];          \
  R6 = hp4[((H0) + 6) * 64 + lane]; R7 = hp4[((H0) + 7) * 64 + lane];

#define PROCB(R0,R1,R2,R3,R4,R5,R6,R7, H0)                                     \
  {                                                                            \
    float p0 = dot4(R0, vhq), p1 = dot4(R1, vhq), p2 = dot4(R2, vhq),          \
          p3 = dot4(R3, vhq), p4 = dot4(R4, vhq), p5 = dot4(R5, vhq),          \
          p6 = dot4(R6, vhq), p7 = dot4(R7, vhq);                              \
    BFLY(p0) BFLY(p1) BFLY(p2) BFLY(p3) BFLY(p4) BFLY(p5) BFLY(p6) BFLY(p7)    \
    p0 = ((mh >> ((H0) + 0)) & 1) ? p0 : -3.0e38f;                             \
    p1 = ((mh >> ((H0) + 1)) & 1) ? p1 : -3.0e38f;                             \
    p2 = ((mh >> ((H0) + 2)) & 1) ? p2 : -3.0e38f;                             \
    p3 = ((mh >> ((H0) + 3)) & 1) ? p3 : -3.0e38f;                             \
    p4 = ((mh >> ((H0) + 4)) & 1) ? p4 : -3.0e38f;                             \
    p5 = ((mh >> ((H0) + 5)) & 1) ? p5 : -3.0e38f;                             \
    p6 = ((mh >> ((H0) + 6)) & 1) ? p6 : -3.0e38f;                             \
    p7 = ((mh >> ((H0) + 7)) & 1) ? p7 : -3.0e38f;                             \
    float pm = fmaxf(fmaxf(fmaxf(p0, p1), fmaxf(p2, p3)),                      \
                     fmaxf(fmaxf(p4, p5), fmaxf(p6, p7)));                     \
    float mn = fmaxf(mrun, pm);                                                \
    float sc = expf(mrun - mn);                                                \
    float e0 = expf(p0 - mn), e1 = expf(p1 - mn), e2 = expf(p2 - mn),          \
          e3 = expf(p3 - mn), e4 = expf(p4 - mn), e5 = expf(p5 - mn),          \
          e6 = expf(p6 - mn), e7 = expf(p7 - mn);                              \
    srun = srun * sc + ((e0 + e1) + (e2 + e3)) + ((e4 + e5) + (e6 + e7));      \
    acc = acc * sc;                                                            \
    acc += e0 * R0; acc += e1 * R1; acc += e2 * R2; acc += e3 * R3;            \
    acc += e4 * R4; acc += e5 * R5; acc += e6 * R6; acc += e7 * R7;            \
    mrun = mn;                                                                 \
  }

__global__ __launch_bounds__(256) void flash_fallback_kernel(
    const float* __restrict__ hist,
    const void* __restrict__ mask_cand_v,
    const void* __restrict__ mask_hist_v,
    const float* __restrict__ ws,
    float* __restrict__ out)
{
  const int tid = threadIdx.x, lane = tid & 63, w = tid >> 6;
  const int b = blockIdx.x * 4 + w;

  const int mode = ((const int*)ws)[ND];
  const f4* hp4 = reinterpret_cast<const f4*>(hist) + (size_t)b * 4096;
  const f4 vhq = reinterpret_cast<const f4*>(ws)[lane];

  const unsigned long long mh =
      __ballot(read_mask(mask_hist_v, b * NH + lane, mode));
  const unsigned long long mc =
      __ballot(read_mask(mask_cand_v, b * NC + lane, mode));

  float mrun = -3.0e38f, srun = 0.f;
  f4 acc = {0.f, 0.f, 0.f, 0.f};
  f4 x0, x1, x2, x3, x4, x5, x6, x7;
  f4 y0, y1, y2, y3, y4, y5, y6, y7;

  LOADB(x0,x1,x2,x3,x4,x5,x6,x7, 0)
  LOADB(y0,y1,y2,y3,y4,y5,y6,y7, 8)
  PROCB(x0,x1,x2,x3,x4,x5,x6,x7, 0)
  LOADB(x0,x1,x2,x3,x4,x5,x6,x7, 16)
  PROCB(y0,y1,y2,y3,y4,y5,y6,y7, 8)
  LOADB(y0,y1,y2,y3,y4,y5,y6,y7, 24)
  PROCB(x0,x1,x2,x3,x4,x5,x6,x7, 16)
  LOADB(x0,x1,x2,x3,x4,x5,x6,x7, 32)
  PROCB(y0,y1,y2,y3,y4,y5,y6,y7, 24)
  LOADB(y0,y1,y2,y3,y4,y5,y6,y7, 40)
  PROCB(x0,x1,x2,x3,x4,x5,x6,x7, 32)
  LOADB(x0,x1,x2,x3,x4,x5,x6,x7, 48)
  PROCB(y0,y1,y2,y3,y4,y5,y6,y7, 40)
  LOADB(y0,y1,y2,y3,y4,y5,y6,y7, 56)
  PROCB(x0,x1,x2,x3,x4,x5,x6,x7, 48)
  PROCB(y0,y1,y2,y3,y4,y5,y6,y7, 56)

  const f4 uv = acc * (1.0f / srun);
  const f4 zero = {0.f, 0.f, 0.f, 0.f};
  f4* ob4 = reinterpret_cast<f4*>(out) + (size_t)b * 4096;
  #pragma unroll
  for (int c = 0; c < 64; ++c)
    ob4[c * 64 + lane] = ((mc >> c) & 1ull) ? uv : zero;
}

extern "C" void kernel_launch(void* const* d_in, const int* in_sizes, int n_in,
                              void* d_out, int out_size, void* d_ws, size_t ws_size,
                              hipStream_t stream) {
  (void)in_sizes; (void)n_in; (void)out_size;
  // inputs: 0 cand [B,C,D] (UNUSED — softmax shift-invariance kills the
  // candidate term), 1 hist [B,H,D], 2 mask_cand, 3 mask_hist,
  // 4 W1 [HID,2D], 5 b1 (unused), 6 W2 [1,HID], 7 b2 (unused)
  const float* hist = (const float*)d_in[1];
  const void*  mask_cand = d_in[2];
  const void*  mask_hist = d_in[3];
  const float* W1 = (const float*)d_in[4];
  const float* W2 = (const float*)d_in[6];
  float* ws = (float*)d_ws;
  float* out = (float*)d_out;

  const bool mid = ws_size >= (size_t)(WS_PART_OFF + 64 * ND) * sizeof(float);
  const bool big = ws_size >= (size_t)WS_NEED_F * sizeof(float);

  if (mid) {
    precompute_p1<<<64, 256, 0, stream>>>(W1, W2, ws);
    precompute_p2<<<1, 256, 0, stream>>>(
        (const unsigned int*)mask_cand, (const unsigned int*)mask_hist, ws);
  } else {
    precompute_fallback<<<1, 1024, 0, stream>>>(
        W1, W2, (const unsigned int*)mask_cand, (const unsigned int*)mask_hist, ws);
  }

  if (big) {
    score2_kernel<<<256, 512, 0, stream>>>(hist, mask_hist, ws);
    bcast2_kernel<<<NB * 4, 256, 0, stream>>>(mask_cand, ws, out);
  } else {
    flash_fallback_kernel<<<NB / 4, 256, 0, stream>>>(hist, mask_cand, mask_hist, ws, out);
  }
}

// Round 15
// 39.926 us; speedup vs baseline: 1.2065x; 1.1496x over previous
//
#include <hip/hip_runtime.h>
#include <math.h>

#define NB 1024
#define NC 64
#define NH 64
#define ND 256
#define NHID 256

typedef float f4 __attribute__((ext_vector_type(4)));

// ws layout (floats): [0..255] = v_h, [256] = mask mode (int),
// [1024 .. 1024+64*256) = P1 partials (needs ws >= 69,632 B)
#define WS_PART_OFF 1024

// Raw barrier with LDS-only drain: DS ops complete, global loads/stores stay
// in flight across the barrier (__syncthreads would drain vmcnt(0)).
#define BAR_LGKM() asm volatile("s_waitcnt lgkmcnt(0)\n\ts_barrier" ::: "memory")

// mask storage modes: 0 = int32, 1 = byte (bool), 2 = float32
__device__ __forceinline__ bool read_mask(const void* m, int idx, int mode) {
  if (mode == 2) return ((const float*)m)[idx] != 0.0f;
  if (mode == 1) return ((const unsigned char*)m)[idx] != 0;
  return ((const int*)m)[idx] != 0;
}

__device__ __forceinline__ void detect_mode(const unsigned int* mask_cand,
                                            const unsigned int* mask_hist,
                                            int* dst) {
  int sawf = 0; unsigned int big = 0;
  for (int i = 0; i < 32; ++i) {
    unsigned int a = mask_hist[i], b = mask_cand[i];
    if (a == 0x3f800000u || b == 0x3f800000u) sawf = 1;
    if ((a > 1u && a != 0x3f800000u) || (b > 1u && b != 0x3f800000u)) big = 1;
  }
  *dst = sawf ? 2 : (big ? 1 : 0);
}

__device__ __forceinline__ float dot4(f4 a, f4 b) {
  return fmaf(a.x, b.x, fmaf(a.y, b.y, fmaf(a.z, b.z, a.w * b.w)));
}

#define BFLY(p) { p += __shfl_xor(p, 32); p += __shfl_xor(p, 16); p += __shfl_xor(p, 8); \
                  p += __shfl_xor(p, 4);  p += __shfl_xor(p, 2);  p += __shfl_xor(p, 1); }

// ---- P1: 64 blocks x 256 threads: partial v_h over 4 j-rows each ----
__global__ __launch_bounds__(256) void precompute_p1(
    const float* __restrict__ W1, const float* __restrict__ W2,
    float* __restrict__ ws)
{
  const int g = blockIdx.x;
  const int d = threadIdx.x;
  float acc = 0.f;
  #pragma unroll
  for (int jj = 0; jj < 4; ++jj) {
    int j = g * 4 + jj;
    acc = fmaf(W1[(size_t)j * (2 * ND) + ND + d], W2[j], acc);
  }
  ws[WS_PART_OFF + g * ND + d] = acc;
}

// ---- P2: 1 block x 256 threads: reduce partials, detect mask mode ----
__global__ __launch_bounds__(256) void precompute_p2(
    const unsigned int* __restrict__ mask_cand,
    const unsigned int* __restrict__ mask_hist,
    float* __restrict__ ws)
{
  const int d = threadIdx.x;
  float acc = 0.f;
  #pragma unroll 8
  for (int g = 0; g < 64; ++g) acc += ws[WS_PART_OFF + g * ND + d];
  ws[d] = acc;
  if (d == 0) detect_mode(mask_cand, mask_hist, (int*)ws + ND);
}

// ---- fallback single-block precompute (small ws) ----
__global__ __launch_bounds__(1024) void precompute_fallback(
    const float* __restrict__ W1, const float* __restrict__ W2,
    const unsigned int* __restrict__ mask_cand,
    const unsigned int* __restrict__ mask_hist,
    float* __restrict__ ws)
{
  __shared__ float w2_lds[NHID];
  __shared__ float partial[4][ND];
  int t = threadIdx.x;
  if (t < NHID) w2_lds[t] = W2[t];
  __syncthreads();
  int d = t & (ND - 1);
  int g = t >> 8;
  float acc = 0.f;
  #pragma unroll 8
  for (int j = g * 64; j < g * 64 + 64; ++j)
    acc = fmaf(W1[(size_t)j * (2 * ND) + ND + d], w2_lds[j], acc);
  partial[g][d] = acc;
  __syncthreads();
  if (t < ND)
    ws[t] = partial[0][t] + partial[1][t] + partial[2][t] + partial[3][t];
  if (t == 0) detect_mode(mask_cand, mask_hist, (int*)ws + ND);
}

// ---- main: 512 blocks x 512 threads; block handles b0 = blockIdx and
// b1 = blockIdx + 512. ALL 16 row-loads (both batches) issue in the
// prologue; barriers are lgkm-only so global traffic streams across them.
// Wave w owns rows w*8..w*8+7 in registers; every global load/store
// instruction is 64 lanes x 16 B = 1 KB contiguous. ----
__global__ __launch_bounds__(512, 4) void fused2_kernel(
    const float* __restrict__ hist,
    const void* __restrict__ mask_cand_v,
    const void* __restrict__ mask_hist_v,
    const float* __restrict__ ws,
    float* __restrict__ out)
{
  const int b0 = blockIdx.x, b1 = blockIdx.x + 512;
  const int t = threadIdx.x, lane = t & 63, w = t >> 6;
  __shared__ float s_lds[2][NH];
  __shared__ f4 red[2][8][64];                   // 16 KB

  const int mode = ((const int*)ws)[ND];
  const f4 vh = reinterpret_cast<const f4*>(ws)[lane];   // 1 KB, L1-hot
  const f4* h0 = reinterpret_cast<const f4*>(hist) + (size_t)b0 * 4096;
  const f4* h1 = reinterpret_cast<const f4*>(hist) + (size_t)b1 * 4096;
  const f4 zero = {0.f, 0.f, 0.f, 0.f};

  // ---- prologue: 16 independent 1 KB-contiguous loads, all in flight ----
  f4 x0 = h0[(w * 8 + 0) * 64 + lane], x1 = h0[(w * 8 + 1) * 64 + lane];
  f4 x2 = h0[(w * 8 + 2) * 64 + lane], x3 = h0[(w * 8 + 3) * 64 + lane];
  f4 x4 = h0[(w * 8 + 4) * 64 + lane], x5 = h0[(w * 8 + 5) * 64 + lane];
  f4 x6 = h0[(w * 8 + 6) * 64 + lane], x7 = h0[(w * 8 + 7) * 64 + lane];
  f4 y0 = h1[(w * 8 + 0) * 64 + lane], y1 = h1[(w * 8 + 1) * 64 + lane];
  f4 y2 = h1[(w * 8 + 2) * 64 + lane], y3 = h1[(w * 8 + 3) * 64 + lane];
  f4 y4 = h1[(w * 8 + 4) * 64 + lane], y5 = h1[(w * 8 + 5) * 64 + lane];
  f4 y6 = h1[(w * 8 + 6) * 64 + lane], y7 = h1[(w * 8 + 7) * 64 + lane];

  // ================= batch 0 =================
  {
    float p0 = dot4(x0, vh), p1 = dot4(x1, vh), p2 = dot4(x2, vh), p3 = dot4(x3, vh);
    float p4 = dot4(x4, vh), p5 = dot4(x5, vh), p6 = dot4(x6, vh), p7 = dot4(x7, vh);
    BFLY(p0) BFLY(p1) BFLY(p2) BFLY(p3) BFLY(p4) BFLY(p5) BFLY(p6) BFLY(p7)
    if (lane < 8) {
      float v = p0;
      if (lane == 1) v = p1;  if (lane == 2) v = p2;  if (lane == 3) v = p3;
      if (lane == 4) v = p4;  if (lane == 5) v = p5;  if (lane == 6) v = p6;
      if (lane == 7) v = p7;
      int h = w * 8 + lane;
      s_lds[0][h] = read_mask(mask_hist_v, b0 * NH + h, mode) ? v : -3.0e38f;
    }
  }
  BAR_LGKM();                       // y-loads remain in flight

  float wval0;
  {
    float s = s_lds[0][lane];
    float m = s;
    m = fmaxf(m, __shfl_xor(m, 32)); m = fmaxf(m, __shfl_xor(m, 16));
    m = fmaxf(m, __shfl_xor(m, 8));  m = fmaxf(m, __shfl_xor(m, 4));
    m = fmaxf(m, __shfl_xor(m, 2));  m = fmaxf(m, __shfl_xor(m, 1));
    float e = expf(s - m);
    float sum = e; BFLY(sum)
    wval0 = e / sum;
  }
  {
    f4 acc = __shfl(wval0, w * 8 + 0) * x0;
    acc += __shfl(wval0, w * 8 + 1) * x1;
    acc += __shfl(wval0, w * 8 + 2) * x2;
    acc += __shfl(wval0, w * 8 + 3) * x3;
    acc += __shfl(wval0, w * 8 + 4) * x4;
    acc += __shfl(wval0, w * 8 + 5) * x5;
    acc += __shfl(wval0, w * 8 + 6) * x6;
    acc += __shfl(wval0, w * 8 + 7) * x7;
    red[0][w][lane] = acc;
  }
  BAR_LGKM();

  {
    f4 uv = red[0][0][lane];
    #pragma unroll
    for (int q = 1; q < 8; ++q) uv += red[0][q][lane];
    f4* ob4 = reinterpret_cast<f4*>(out) + (size_t)b0 * 4096;
    #pragma unroll
    for (int j = 0; j < 8; ++j) {
      int c = w * 8 + j;
      bool mc = read_mask(mask_cand_v, b0 * NC + c, mode);
      ob4[c * 64 + lane] = mc ? uv : zero;      // stores overlap batch-1 compute
    }
  }

  // ================= batch 1 =================
  {
    float p0 = dot4(y0, vh), p1 = dot4(y1, vh), p2 = dot4(y2, vh), p3 = dot4(y3, vh);
    float p4 = dot4(y4, vh), p5 = dot4(y5, vh), p6 = dot4(y6, vh), p7 = dot4(y7, vh);
    BFLY(p0) BFLY(p1) BFLY(p2) BFLY(p3) BFLY(p4) BFLY(p5) BFLY(p6) BFLY(p7)
    if (lane < 8) {
      float v = p0;
      if (lane == 1) v = p1;  if (lane == 2) v = p2;  if (lane == 3) v = p3;
      if (lane == 4) v = p4;  if (lane == 5) v = p5;  if (lane == 6) v = p6;
      if (lane == 7) v = p7;
      int h = w * 8 + lane;
      s_lds[1][h] = read_mask(mask_hist_v, b1 * NH + h, mode) ? v : -3.0e38f;
    }
  }
  BAR_LGKM();

  float wval1;
  {
    float s = s_lds[1][lane];
    float m = s;
    m = fmaxf(m, __shfl_xor(m, 32)); m = fmaxf(m, __shfl_xor(m, 16));
    m = fmaxf(m, __shfl_xor(m, 8));  m = fmaxf(m, __shfl_xor(m, 4));
    m = fmaxf(m, __shfl_xor(m, 2));  m = fmaxf(m, __shfl_xor(m, 1));
    float e = expf(s - m);
    float sum = e; BFLY(sum)
    wval1 = e / sum;
  }
  {
    f4 acc = __shfl(wval1, w * 8 + 0) * y0;
    acc += __shfl(wval1, w * 8 + 1) * y1;
    acc += __shfl(wval1, w * 8 + 2) * y2;
    acc += __shfl(wval1, w * 8 + 3) * y3;
    acc += __shfl(wval1, w * 8 + 4) * y4;
    acc += __shfl(wval1, w * 8 + 5) * y5;
    acc += __shfl(wval1, w * 8 + 6) * y6;
    acc += __shfl(wval1, w * 8 + 7) * y7;
    red[1][w][lane] = acc;
  }
  BAR_LGKM();

  {
    f4 uv = red[1][0][lane];
    #pragma unroll
    for (int q = 1; q < 8; ++q) uv += red[1][q][lane];
    f4* ob4 = reinterpret_cast<f4*>(out) + (size_t)b1 * 4096;
    #pragma unroll
    for (int j = 0; j < 8; ++j) {
      int c = w * 8 + j;
      bool mc = read_mask(mask_cand_v, b1 * NC + c, mode);
      ob4[c * 64 + lane] = mc ? uv : zero;
    }
  }
}

extern "C" void kernel_launch(void* const* d_in, const int* in_sizes, int n_in,
                              void* d_out, int out_size, void* d_ws, size_t ws_size,
                              hipStream_t stream) {
  (void)in_sizes; (void)n_in; (void)out_size;
  // inputs: 0 cand [B,C,D] (UNUSED — softmax shift-invariance kills the
  // candidate term), 1 hist [B,H,D], 2 mask_cand, 3 mask_hist,
  // 4 W1 [HID,2D], 5 b1 (unused), 6 W2 [1,HID], 7 b2 (unused)
  const float* hist = (const float*)d_in[1];
  const void*  mask_cand = d_in[2];
  const void*  mask_hist = d_in[3];
  const float* W1 = (const float*)d_in[4];
  const float* W2 = (const float*)d_in[6];
  float* ws = (float*)d_ws;
  float* out = (float*)d_out;

  if (ws_size >= (size_t)(WS_PART_OFF + 64 * ND) * sizeof(float)) {
    precompute_p1<<<64, 256, 0, stream>>>(W1, W2, ws);
    precompute_p2<<<1, 256, 0, stream>>>(
        (const unsigned int*)mask_cand, (const unsigned int*)mask_hist, ws);
  } else {
    precompute_fallback<<<1, 1024, 0, stream>>>(
        W1, W2, (const unsigned int*)mask_cand, (const unsigned int*)mask_hist, ws);
  }
  fused2_kernel<<<NB / 2, 512, 0, stream>>>(hist, mask_cand, mask_hist, ws, out);
}